// Round 12
// baseline (8761.169 us; speedup 1.0000x reference)
//
#include <hip/hip_runtime.h>
#include <stdint.h>

// ---------------- problem constants ----------------
#define TSTEPS 512
#define NB     256
#define DIN    85
#define DPAD   96
#define HID    512
#define ODIM   33
#define OPAD   48
#define TBROWS (TSTEPS*NB)
#define NBLK   256          // 16 strips x 16 parts
#define SROWS  16
#define LROW   520          // padded LDS row stride (u16)

typedef unsigned int u32;
typedef unsigned short u16;
typedef unsigned long long u64;
typedef __bf16 bf16x8 __attribute__((ext_vector_type(8)));
typedef float  f32x4  __attribute__((ext_vector_type(4)));

__device__ __forceinline__ u16 f2bf(float f) {
  u32 u = __float_as_uint(f);
  return (u16)((u + 0x7FFFu + ((u >> 16) & 1u)) >> 16);   // RNE
}
__device__ __forceinline__ float bf2f(u16 h) {
  return __uint_as_float(((u32)h) << 16);
}
__device__ __forceinline__ bf16x8 bc8(uint4 v) { return __builtin_bit_cast(bf16x8, v); }
__device__ __forceinline__ f32x4 mfma_bf16(bf16x8 a, bf16x8 b, f32x4 c) {
  return __builtin_amdgcn_mfma_f32_16x16x32_bf16(a, b, c, 0, 0, 0);
}
__device__ __forceinline__ float fsigmoid(float x) { return 1.0f / (1.0f + __expf(-x)); }
__device__ __forceinline__ float ftanh(float x)    { return 2.0f / (1.0f + __expf(-2.0f*x)) - 1.0f; }

// agent-scope (LLC-coherent) relaxed ops for cross-block mutable data
__device__ __forceinline__ void st_u32_llc(u32* p, u32 v) {
  __hip_atomic_store(p, v, __ATOMIC_RELAXED, __HIP_MEMORY_SCOPE_AGENT);
}
__device__ __forceinline__ u32 ld_u32_llc(const u32* p) {
  return __hip_atomic_load(p, __ATOMIC_RELAXED, __HIP_MEMORY_SCOPE_AGENT);
}
__device__ __forceinline__ u64 ld_u64_llc(const u64* p) {
  return __hip_atomic_load(p, __ATOMIC_RELAXED, __HIP_MEMORY_SCOPE_AGENT);
}
#define POLL_FENCE() do { asm volatile("" ::: "memory"); __builtin_amdgcn_sched_barrier(0); } while (0)

// ---------------- prep: bf16 weight conversions ----------------
__global__ void __launch_bounds__(256) prep_kernel(
    const float* __restrict__ Whr, const float* __restrict__ Whz, const float* __restrict__ Whh,
    const float* __restrict__ Wxr, const float* __restrict__ Wxz, const float* __restrict__ Wxh,
    const float* __restrict__ Wro,
    u16* __restrict__ w_hb, u16* __restrict__ wx_hi, u16* __restrict__ wx_lo,
    u16* __restrict__ w_rob)
{
  int tid = blockIdx.x * blockDim.x + threadIdx.x;
  int np  = gridDim.x * blockDim.x;
  for (int i = tid; i < 3 * HID * HID; i += np) {
    int m = i / (HID * HID), r = i % (HID * HID);
    const float* src = (m == 0) ? Whr : ((m == 1) ? Whz : Whh);
    w_hb[i] = f2bf(src[r]);
  }
  for (int i = tid; i < 3 * HID * DPAD; i += np) {
    int m = i / (HID * DPAD), r = i % (HID * DPAD);
    int row = r / DPAD, k = r % DPAD;
    const float* src = (m == 0) ? Wxr : ((m == 1) ? Wxz : Wxh);
    u16 hi = 0, lo = 0;
    if (k < DIN) {
      float v = src[row * DIN + k];
      hi = f2bf(v);
      lo = f2bf(v - bf2f(hi));
    }
    wx_hi[i] = hi; wx_lo[i] = lo;
  }
  for (int i = tid; i < OPAD * HID; i += np) {
    int row = i / HID, k = i % HID;
    w_rob[i] = (row < ODIM) ? f2bf(Wro[row * HID + k]) : (u16)0;
  }
}

// ---------------- persistent recurrence kernel ----------------
// R5 flag protocol (drain -> flag -> poll), Z GEMM hidden in the g-flight window.
__global__ void __launch_bounds__(256, 1) recur_kernel(
    const float* __restrict__ x,  const float* __restrict__ nr,
    const float* __restrict__ nz, const float* __restrict__ nh,
    const float* __restrict__ bhr, const float* __restrict__ bhz, const float* __restrict__ bhh,
    const u16* __restrict__ wx_hi, const u16* __restrict__ wx_lo, const u16* __restrict__ w_hb,
    u32* __restrict__ h_pk, u32* __restrict__ g_pk, u32* __restrict__ flags,
    u16* __restrict__ hs_out,
    const float* __restrict__ Wro, const float* __restrict__ bro, float* __restrict__ out,
    int do_c)
{
  __shared__ __attribute__((aligned(16))) u16 sBig[2 * SROWS * LROW];   // 33280 B
  __shared__ __attribute__((aligned(16))) u16 sX[3][2][SROWS][104];     // 19968 B
  __shared__ __attribute__((aligned(16))) float sC[2][2][64][4];        // 4096 B

  u16 (*sHh)[LROW] = (u16(*)[LROW])sBig;
  u16 (*sHl)[LROW] = (u16(*)[LROW])(sBig + SROWS * LROW);
  u16 (*sGh)[LROW] = sHh;
  u16 (*sGl)[LROW] = sHl;

  const int tid  = threadIdx.x;
  const int lane = tid & 63;
  const int wave = tid >> 6;
  const int strip = (int)blockIdx.x >> 4;    // 0..15 (16 batch rows)
  const int part  = (int)blockIdx.x & 15;    // 0..15 (32 cols)
  const int kh = wave >> 1;                  // k-half
  const int ct = wave & 1;                   // col-tile
  const int rowl  = lane & 15;
  const int rquad = lane >> 4;
  const int scol  = part * 32 + ct * 16 + rowl;

  u32* flagA = flags + strip * 32;           // g ready
  u32* flagB = flags + strip * 32 + 16;      // h ready

  const u16* WR = w_hb;
  const u16* WZ = w_hb + (size_t)HID * HID;
  const u16* WH = w_hb + (size_t)2 * HID * HID;
  const u16* WXRh = wx_hi;                          const u16* WXRl = wx_lo;
  const u16* WXZh = wx_hi + (size_t)HID * DPAD;     const u16* WXZl = wx_lo + (size_t)HID * DPAD;
  const u16* WXHh = wx_hi + (size_t)2 * HID * DPAD; const u16* WXHl = wx_lo + (size_t)2 * HID * DPAD;

  const float bRv = bhr[scol], bZv = bhz[scol], bHv = bhh[scol];

  float h_old[4] = {0.f, 0.f, 0.f, 0.f};
  float zv[4]    = {0.f, 0.f, 0.f, 0.f};

  // zero x k-pads once
  for (int c = tid; c < 3 * 2 * SROWS * (104 - DIN); c += 256) {
    int g = c / (2 * SROWS * 19), r1 = c % (2 * SROWS * 19);
    int pl = r1 / (SROWS * 19),   r2 = r1 % (SROWS * 19);
    int row = r2 / 19, k = DIN + r2 % 19;
    sX[g][pl][row][k] = 0;
  }
  // stage x(1)
  {
    const size_t xbase = (size_t)(strip * SROWS) * DIN;
    for (int c = tid; c < 3 * SROWS * DIN; c += 256) {
      int g = c / (SROWS * DIN), rem = c - g * (SROWS * DIN);
      int row = rem / DIN, k = rem - row * DIN;
      const float* nsrc = (g == 0) ? nr : ((g == 1) ? nz : nh);
      float v = x[xbase + rem] + nsrc[xbase + rem];
      u16 hi = f2bf(v);
      sX[g][0][row][k] = hi;
      sX[g][1][row][k] = f2bf(v - bf2f(hi));
    }
  }
  __syncthreads();

  for (int t = 1; t <= TSTEPS; ++t) {
    // ---- poll h(t-1) flag (wave 0; waves 1-3 idle at barrier after restage) ----
    if (wave == 0 && t > 1) {
      const u32 target = (u32)(t - 1);
      for (;;) {
        u32 a = (lane < 16) ? ld_u32_llc(&flagB[lane]) : target;
        if (__all(a >= target)) break;
      }
      POLL_FENCE();
    }
    __syncthreads();

    // ---- stage h(t-1) strip: 16 u64/thread, one shot ----
    {
      const u64* hsrc = (const u64*)h_pk + (size_t)strip * SROWS * 256;
      u64 hreg[SROWS];
      #pragma unroll
      for (int i = 0; i < SROWS; ++i)
        hreg[i] = ld_u64_llc(&hsrc[(size_t)i * 256 + tid]);
      #pragma unroll
      for (int i = 0; i < SROWS; ++i) {
        u32 v0 = (u32)hreg[i], v1 = (u32)(hreg[i] >> 32);
        *(u32*)&sHh[i][tid * 2] = (v0 >> 16) | (v1 & 0xFFFF0000u);
        *(u32*)&sHl[i][tid * 2] = (v0 & 0xFFFFu) | (v1 << 16);
      }
    }
    __syncthreads();

    // ================= R-only GEMM (get g out the door fast) =================
    f32x4 aR = {0.f, 0.f, 0.f, 0.f};
    if (kh == 0) {
      #pragma unroll
      for (int ks = 0; ks < 3; ++ks) {
        int kk = ks * 32 + rquad * 8;
        bf16x8 xrh = bc8(*(const uint4*)&sX[0][0][rowl][kk]);
        bf16x8 xrl = bc8(*(const uint4*)&sX[0][1][rowl][kk]);
        bf16x8 wrh = bc8(*(const uint4*)&WXRh[(size_t)scol * DPAD + kk]);
        bf16x8 wrl = bc8(*(const uint4*)&WXRl[(size_t)scol * DPAD + kk]);
        aR = mfma_bf16(xrh, wrh, aR);
        aR = mfma_bf16(xrl, wrh, aR);
        aR = mfma_bf16(xrh, wrl, aR);
      }
    }
    #pragma unroll
    for (int c = 0; c < 8; ++c) {
      int k = (kh * 8 + c) * 32 + rquad * 8;
      bf16x8 ah = bc8(*(const uint4*)&sHh[rowl][k]);
      bf16x8 al = bc8(*(const uint4*)&sHl[rowl][k]);
      bf16x8 bwR = bc8(*(const uint4*)&WR[(size_t)scol * HID + k]);
      aR = mfma_bf16(ah, bwR, aR);
      aR = mfma_bf16(al, bwR, aR);
    }
    if (kh == 1) *(f32x4*)&sC[0][ct][lane][0] = aR;
    __syncthreads();
    if (kh == 0) {
      f32x4 oR = *(const f32x4*)&sC[0][ct][lane][0];
      #pragma unroll
      for (int r = 0; r < 4; ++r) {
        int rowm = rquad * 4 + r;
        float Rv = fsigmoid(aR[r] + oR[r] + bRv);
        float hprec = bf2f(sHh[rowm][scol]) + bf2f(sHl[rowm][scol]);
        float g = Rv * hprec;
        u16 gh = f2bf(g);
        u16 gl = f2bf(g - bf2f(gh));
        st_u32_llc(&g_pk[(size_t)(strip * SROWS + rowm) * HID + scol],
                   ((u32)gh << 16) | (u32)gl);
      }
    }
    __syncthreads();   // drain g stores (vmcnt 0 for all waves)
    if (tid == 0) st_u32_llc(&flagA[part], (u32)t);

    // ================= Z GEMM: fills the g-flight window (reads sH, stays in regs) ====
    f32x4 aZ = {0.f, 0.f, 0.f, 0.f};
    if (kh == 0) {
      #pragma unroll
      for (int ks = 0; ks < 3; ++ks) {
        int kk = ks * 32 + rquad * 8;
        bf16x8 xzh = bc8(*(const uint4*)&sX[1][0][rowl][kk]);
        bf16x8 xzl = bc8(*(const uint4*)&sX[1][1][rowl][kk]);
        bf16x8 wzh = bc8(*(const uint4*)&WXZh[(size_t)scol * DPAD + kk]);
        bf16x8 wzl = bc8(*(const uint4*)&WXZl[(size_t)scol * DPAD + kk]);
        aZ = mfma_bf16(xzh, wzh, aZ);
        aZ = mfma_bf16(xzl, wzh, aZ);
        aZ = mfma_bf16(xzh, wzl, aZ);
      }
    }
    #pragma unroll
    for (int c = 0; c < 8; ++c) {
      int k = (kh * 8 + c) * 32 + rquad * 8;
      bf16x8 ah = bc8(*(const uint4*)&sHh[rowl][k]);
      bf16x8 al = bc8(*(const uint4*)&sHl[rowl][k]);
      bf16x8 bwZ = bc8(*(const uint4*)&WZ[(size_t)scol * HID + k]);
      aZ = mfma_bf16(ah, bwZ, aZ);
      aZ = mfma_bf16(al, bwZ, aZ);
    }
    if (kh == 1) *(f32x4*)&sC[1][ct][lane][0] = aZ;
    __syncthreads();
    if (kh == 0) {
      f32x4 oZ = *(const f32x4*)&sC[1][ct][lane][0];
      #pragma unroll
      for (int r = 0; r < 4; ++r) zv[r] = fsigmoid(aZ[r] + oZ[r] + bZv);
    }

    // ---- phase C (small-ws): out(t-2) from sH = h(t-1), also in the g window ----
    if (do_c && t >= 2) {
      __syncthreads();
      float* scz = (float*)sC;
      const int o = tid >> 3, q = tid & 7;
      float a = 0.f;
      #pragma unroll 8
      for (int k2 = 0; k2 < 64; ++k2) {
        int k = q * 64 + k2;
        a += (bf2f(sHh[part][k]) + bf2f(sHl[part][k])) * Wro[(size_t)o * HID + k];
      }
      scz[o * 8 + q] = a;
      if (tid < 8) {
        float a2 = 0.f;
        #pragma unroll 8
        for (int k2 = 0; k2 < 64; ++k2) {
          int k = tid * 64 + k2;
          a2 += (bf2f(sHh[part][k]) + bf2f(sHl[part][k])) * Wro[(size_t)32 * HID + k];
        }
        scz[256 + tid] = a2;
      }
      __syncthreads();
      if (tid < ODIM) {
        float s = bro[tid];
        #pragma unroll
        for (int q2 = 0; q2 < 8; ++q2) s += scz[tid * 8 + q2];
        out[(size_t)((t - 2) * NB + strip * SROWS + part) * ODIM + tid] = s;
      }
    }

    // ---- poll g flag, stage g over the h planes ----
    if (wave == 0) {
      const u32 target = (u32)t;
      for (;;) {
        u32 a = (lane < 16) ? ld_u32_llc(&flagA[lane]) : target;
        if (__all(a >= target)) break;
      }
      POLL_FENCE();
    }
    __syncthreads();                 // also orders: all sH reads complete before overwrite
    {
      const u64* gsrc = (const u64*)g_pk + (size_t)strip * SROWS * 256;
      u64 greg[SROWS];
      #pragma unroll
      for (int i = 0; i < SROWS; ++i)
        greg[i] = ld_u64_llc(&gsrc[(size_t)i * 256 + tid]);
      #pragma unroll
      for (int i = 0; i < SROWS; ++i) {
        u32 v0 = (u32)greg[i], v1 = (u32)(greg[i] >> 32);
        *(u32*)&sGh[i][tid * 2] = (v0 >> 16) | (v1 & 0xFFFF0000u);
        *(u32*)&sGl[i][tid * 2] = (v0 & 0xFFFFu) | (v1 << 16);
      }
    }
    __syncthreads();

    // ================= Hhat GEMM + state update =================
    f32x4 aH = {0.f, 0.f, 0.f, 0.f};
    if (kh == 0) {
      #pragma unroll
      for (int ks = 0; ks < 3; ++ks) {
        int kk = ks * 32 + rquad * 8;
        bf16x8 xhh = bc8(*(const uint4*)&sX[2][0][rowl][kk]);
        bf16x8 xhl = bc8(*(const uint4*)&sX[2][1][rowl][kk]);
        bf16x8 whh = bc8(*(const uint4*)&WXHh[(size_t)scol * DPAD + kk]);
        bf16x8 whl = bc8(*(const uint4*)&WXHl[(size_t)scol * DPAD + kk]);
        aH = mfma_bf16(xhh, whh, aH);
        aH = mfma_bf16(xhl, whh, aH);
        aH = mfma_bf16(xhh, whl, aH);
      }
    }
    #pragma unroll
    for (int c = 0; c < 8; ++c) {
      int k = (kh * 8 + c) * 32 + rquad * 8;
      bf16x8 gh8 = bc8(*(const uint4*)&sGh[rowl][k]);
      bf16x8 gl8 = bc8(*(const uint4*)&sGl[rowl][k]);
      bf16x8 bwH = bc8(*(const uint4*)&WH[(size_t)scol * HID + k]);
      aH = mfma_bf16(gh8, bwH, aH);
      aH = mfma_bf16(gl8, bwH, aH);
    }
    if (kh == 1) *(f32x4*)&sC[0][ct][lane][0] = aH;
    __syncthreads();

    u16 hiv[4];
    if (kh == 0) {
      f32x4 oH = *(const f32x4*)&sC[0][ct][lane][0];
      #pragma unroll
      for (int r = 0; r < 4; ++r) {
        int rowm = rquad * 4 + r;
        float Hv = ftanh(aH[r] + oH[r] + bHv);
        float hn = zv[r] * h_old[r] + (1.0f - zv[r]) * Hv;
        h_old[r] = hn;
        u16 hi = f2bf(hn);
        u16 lo = f2bf(hn - bf2f(hi));
        hiv[r] = hi;
        st_u32_llc(&h_pk[(size_t)(strip * SROWS + rowm) * HID + scol],
                   ((u32)hi << 16) | (u32)lo);
      }
    }
    __syncthreads();   // drain h stores
    if (tid == 0) st_u32_llc(&flagB[part], (u32)t);

    // ---- off the critical path: hs_out (big-ws) + x(t+1) restage by waves 1-3 ----
    if (hs_out && kh == 0) {
      #pragma unroll
      for (int r = 0; r < 4; ++r)
        hs_out[(size_t)((t - 1) * NB + strip * SROWS + rquad * 4 + r) * HID + scol] = hiv[r];
    }
    if (t < TSTEPS && wave != 0) {
      const size_t xbase = ((size_t)t * NB + strip * SROWS) * DIN;
      for (int c = tid - 64; c < 3 * SROWS * DIN; c += 192) {
        int g = c / (SROWS * DIN), rem = c - g * (SROWS * DIN);
        int row = rem / DIN, k = rem - row * DIN;
        const float* nsrc = (g == 0) ? nr : ((g == 1) ? nz : nh);
        float v = x[xbase + rem] + nsrc[xbase + rem];
        u16 hi = f2bf(v);
        sX[g][0][row][k] = hi;
        sX[g][1][row][k] = f2bf(v - bf2f(hi));
      }
    }
  }

  // ---- final phase C (small-ws): out(TSTEPS-1) from h(TSTEPS) ----
  if (do_c) {
    if (wave == 0) {
      const u32 target = (u32)TSTEPS;
      for (;;) {
        u32 a = (lane < 16) ? ld_u32_llc(&flagB[lane]) : target;
        if (__all(a >= target)) break;
      }
      POLL_FENCE();
    }
    __syncthreads();
    const u64* hrow = (const u64*)h_pk + (size_t)(strip * SROWS + part) * 256;
    u64 v = ld_u64_llc(&hrow[tid]);
    float* scz = (float*)sC;    // [0..511] row values, [512..783] partials
    {
      u32 a0 = (u32)v, a1 = (u32)(v >> 32);
      scz[tid * 2]     = bf2f((u16)(a0 >> 16)) + bf2f((u16)(a0 & 0xFFFFu));
      scz[tid * 2 + 1] = bf2f((u16)(a1 >> 16)) + bf2f((u16)(a1 & 0xFFFFu));
    }
    __syncthreads();
    float* sp = scz + 512;
    const int o = tid >> 3, q = tid & 7;
    float a = 0.f;
    #pragma unroll 8
    for (int k2 = 0; k2 < 64; ++k2) {
      int k = q * 64 + k2;
      a += scz[k] * Wro[(size_t)o * HID + k];
    }
    sp[o * 8 + q] = a;
    if (tid < 8) {
      float a2 = 0.f;
      #pragma unroll 8
      for (int k2 = 0; k2 < 64; ++k2) {
        int k = tid * 64 + k2;
        a2 += scz[k] * Wro[(size_t)32 * HID + k];
      }
      sp[256 + tid] = a2;
    }
    __syncthreads();
    if (tid < ODIM) {
      float s = bro[tid];
      #pragma unroll
      for (int q2 = 0; q2 < 8; ++q2) s += sp[tid * 8 + q2];
      out[(size_t)((TSTEPS - 1) * NB + strip * SROWS + part) * ODIM + tid] = s;
    }
  }
}

// ---------------- output projection (big-ws path) ----------------
__global__ void __launch_bounds__(256) out_kernel(
    const u16* __restrict__ hs_out,
    const u16* __restrict__ w_rob, const float* __restrict__ b_ro,
    float* __restrict__ out)
{
  __shared__ __attribute__((aligned(16))) u16 sOh[128][72];

  const int m0   = blockIdx.x * 128;
  const int tid  = threadIdx.x;
  const int lane = tid & 63, wave = tid >> 6;

  f32x4 acc[2][3];
  for (int a = 0; a < 2; ++a) for (int b = 0; b < 3; ++b) acc[a][b] = {0.f, 0.f, 0.f, 0.f};

  for (int kc = 0; kc < 8; ++kc) {
    __syncthreads();
    #pragma unroll
    for (int i = 0; i < 4; ++i) {
      int c = tid + 256 * i; int row = c >> 3, seg = c & 7;
      *(uint4*)&sOh[row][seg * 8] =
        *(const uint4*)&hs_out[(size_t)(m0 + row) * HID + kc * 64 + seg * 8];
    }
    __syncthreads();
    #pragma unroll
    for (int ks = 0; ks < 2; ++ks) {
      int klocal = ks * 32 + 8 * (lane >> 4);
      int kglob  = kc * 64 + klocal;
      bf16x8 ah[2];
      #pragma unroll
      for (int mf = 0; mf < 2; ++mf) {
        int rowl = wave * 32 + mf * 16 + (lane & 15);
        ah[mf] = bc8(*(const uint4*)&sOh[rowl][klocal]);
      }
      #pragma unroll
      for (int nf = 0; nf < 3; ++nf) {
        int wrow = nf * 16 + (lane & 15);
        bf16x8 bw = bc8(*(const uint4*)&w_rob[(size_t)wrow * HID + kglob]);
        #pragma unroll
        for (int mf = 0; mf < 2; ++mf)
          acc[mf][nf] = mfma_bf16(ah[mf], bw, acc[mf][nf]);
      }
    }
  }
  for (int nf = 0; nf < 3; ++nf) {
    int o = nf * 16 + (lane & 15);
    if (o < ODIM) {
      float bb = b_ro[o];
      for (int mf = 0; mf < 2; ++mf)
        for (int r = 0; r < 4; ++r) {
          int R = m0 + wave * 32 + mf * 16 + (lane >> 4) * 4 + r;
          out[(size_t)R * ODIM + o] = acc[mf][nf][r] + bb;
        }
    }
  }
}

// ---------------- launcher ----------------
extern "C" void kernel_launch(void* const* d_in, const int* in_sizes, int n_in,
                              void* d_out, int out_size, void* d_ws, size_t ws_size,
                              hipStream_t stream)
{
  const float* x   = (const float*)d_in[0];
  const float* nr  = (const float*)d_in[1];
  const float* nz  = (const float*)d_in[2];
  const float* nh  = (const float*)d_in[3];
  const float* Wxr = (const float*)d_in[4];
  const float* Wxz = (const float*)d_in[5];
  const float* Wxh = (const float*)d_in[6];
  const float* Whr = (const float*)d_in[7];
  const float* bhr = (const float*)d_in[8];
  const float* Whz = (const float*)d_in[9];
  const float* bhz = (const float*)d_in[10];
  const float* Whh = (const float*)d_in[11];
  const float* bhh = (const float*)d_in[12];
  const float* Wro = (const float*)d_in[13];
  const float* bro = (const float*)d_in[14];
  float* out = (float*)d_out;

  char* ws = (char*)d_ws;
  size_t off = 0;
  auto alloc = [&](size_t bytes) -> char* {
    char* p = ws + off;
    off += (bytes + 255) & ~(size_t)255;
    return p;
  };
  u32*  h_pk  = (u32*) alloc((size_t)NB * HID * 4);       // packed hi|lo h (single buffer)
  u32*  g_pk  = (u32*) alloc((size_t)NB * HID * 4);       // packed hi|lo R*h (single buffer)
  u16*  w_hb  = (u16*) alloc((size_t)3 * HID * HID * 2);
  u16*  wx_hi = (u16*) alloc((size_t)3 * HID * DPAD * 2);
  u16*  wx_lo = (u16*) alloc((size_t)3 * HID * DPAD * 2);
  u16*  w_rob = (u16*) alloc((size_t)OPAD * HID * 2);
  u32*  flags = (u32*) alloc((size_t)16 * 32 * 4);        // 16 strips x 2 lines
  size_t small_need = off;
  if (ws_size < small_need) return;   // fail numerically, never scribble

  u16* hs_out = (u16*)(ws + off);
  size_t big_need = off + (size_t)TBROWS * HID * 2 + 256;
  bool big = (ws_size >= big_need);
  if (!big) hs_out = nullptr;

  hipMemsetAsync(flags, 0, (size_t)16 * 32 * 4, stream);
  hipMemsetAsync(h_pk,  0, (size_t)NB * HID * 4, stream);   // h(0) = 0

  prep_kernel<<<512, 256, 0, stream>>>(Whr, Whz, Whh, Wxr, Wxz, Wxh, Wro,
                                       w_hb, wx_hi, wx_lo, w_rob);

  recur_kernel<<<NBLK, 256, 0, stream>>>(
      x, nr, nz, nh, bhr, bhz, bhh, wx_hi, wx_lo, w_hb,
      h_pk, g_pk, flags, hs_out, Wro, bro, out, big ? 0 : 1);

  if (big)
    out_kernel<<<TBROWS / 128, 256, 0, stream>>>(hs_out, w_rob, bro, out);
}

// Round 13
// 5259.217 us; speedup vs baseline: 1.6659x; 1.6659x over previous
//
#include <hip/hip_runtime.h>
#include <stdint.h>

// ---------------- problem constants ----------------
#define TSTEPS 512
#define NB     256
#define DIN    85
#define DPAD   96
#define HID    512
#define ODIM   33
#define OPAD   48
#define TBROWS (TSTEPS*NB)
#define NBLK   256          // 16 strip-groups x 16 parts; 42KB LDS, deadlock-proof residency
#define SROWS  16           // batch rows per strip-group

typedef unsigned int u32;
typedef unsigned short u16;
typedef unsigned long long u64;
typedef __bf16 bf16x8 __attribute__((ext_vector_type(8)));
typedef float  f32x4  __attribute__((ext_vector_type(4)));

__device__ __forceinline__ u16 f2bf(float f) {
  u32 u = __float_as_uint(f);
  return (u16)((u + 0x7FFFu + ((u >> 16) & 1u)) >> 16);   // RNE
}
__device__ __forceinline__ float bf2f(u16 h) {
  return __uint_as_float(((u32)h) << 16);
}
__device__ __forceinline__ bf16x8 bc8(uint4 v) { return __builtin_bit_cast(bf16x8, v); }
__device__ __forceinline__ f32x4 mfma_bf16(bf16x8 a, bf16x8 b, f32x4 c) {
  return __builtin_amdgcn_mfma_f32_16x16x32_bf16(a, b, c, 0, 0, 0);
}
__device__ __forceinline__ float fsigmoid(float x) { return 1.0f / (1.0f + __expf(-x)); }
__device__ __forceinline__ float ftanh(float x)    { return 2.0f / (1.0f + __expf(-2.0f*x)) - 1.0f; }

// agent-scope (LLC-coherent) relaxed ops for cross-block mutable data
// (ordering for the flag protocol comes from __syncthreads()'s vmcnt(0) drain)
__device__ __forceinline__ void st_u32_llc(u32* p, u32 v) {
  __hip_atomic_store(p, v, __ATOMIC_RELAXED, __HIP_MEMORY_SCOPE_AGENT);
}
__device__ __forceinline__ u32 ld_u32_llc(const u32* p) {
  return __hip_atomic_load(p, __ATOMIC_RELAXED, __HIP_MEMORY_SCOPE_AGENT);
}
__device__ __forceinline__ u64 ld_u64_llc(const u64* p) {
  return __hip_atomic_load(p, __ATOMIC_RELAXED, __HIP_MEMORY_SCOPE_AGENT);
}
__device__ __forceinline__ void st_f32_llc(float* p, float v) {
  __hip_atomic_store(p, v, __ATOMIC_RELAXED, __HIP_MEMORY_SCOPE_AGENT);
}
__device__ __forceinline__ float ld_f32_llc(const float* p) {
  return __hip_atomic_load(p, __ATOMIC_RELAXED, __HIP_MEMORY_SCOPE_AGENT);
}

// ---------------- prep: bf16 weight conversions ----------------
__global__ void __launch_bounds__(256) prep_kernel(
    const float* __restrict__ Whr, const float* __restrict__ Whz, const float* __restrict__ Whh,
    const float* __restrict__ Wxr, const float* __restrict__ Wxz, const float* __restrict__ Wxh,
    const float* __restrict__ Wro,
    u16* __restrict__ w_hb, u16* __restrict__ wx_hi, u16* __restrict__ wx_lo,
    u16* __restrict__ w_rob)
{
  int tid = blockIdx.x * blockDim.x + threadIdx.x;
  int np  = gridDim.x * blockDim.x;
  for (int i = tid; i < 3 * HID * HID; i += np) {
    int m = i / (HID * HID), r = i % (HID * HID);
    const float* src = (m == 0) ? Whr : ((m == 1) ? Whz : Whh);
    w_hb[i] = f2bf(src[r]);
  }
  for (int i = tid; i < 3 * HID * DPAD; i += np) {
    int m = i / (HID * DPAD), r = i % (HID * DPAD);
    int row = r / DPAD, k = r % DPAD;
    const float* src = (m == 0) ? Wxr : ((m == 1) ? Wxz : Wxh);
    u16 hi = 0, lo = 0;
    if (k < DIN) {
      float v = src[row * DIN + k];
      hi = f2bf(v);
      lo = f2bf(v - bf2f(hi));
    }
    wx_hi[i] = hi; wx_lo[i] = lo;
  }
  for (int i = tid; i < OPAD * HID; i += np) {
    int row = i / HID, k = i % HID;
    w_rob[i] = (row < ODIM) ? f2bf(Wro[row * HID + k]) : (u16)0;
  }
}

// ---------------- persistent recurrence kernel ----------------
#define LROW 520   // padded LDS row stride (u16)

__global__ void __launch_bounds__(256, 1) recur_kernel(
    const float* __restrict__ x,  const float* __restrict__ nr,
    const float* __restrict__ nz, const float* __restrict__ nh,
    const float* __restrict__ bhr, const float* __restrict__ bhz, const float* __restrict__ bhh,
    const u16* __restrict__ wx_hi, const u16* __restrict__ wx_lo, const u16* __restrict__ w_hb,
    u32* __restrict__ h_pk, u32* __restrict__ g_pk,
    float* __restrict__ z_buf, u32* __restrict__ flags,
    u16* __restrict__ hs_out,
    const float* __restrict__ Wro, const float* __restrict__ bro, float* __restrict__ out,
    int do_c)
{
  // union strip buffer: A = split h (hi,lo); B = split g (hi,lo); C = f32 scratch
  __shared__ __attribute__((aligned(16))) u16 sBig[2 * SROWS * LROW];   // 33280 B
  __shared__ __attribute__((aligned(16))) u16 sXh[SROWS][104];          // 3328 B
  __shared__ __attribute__((aligned(16))) u16 sXl[SROWS][104];          // 3328 B
  __shared__ __attribute__((aligned(16))) float sC[2][64][4];           // 2048 B

  u16 (*sHh)[LROW] = (u16(*)[LROW])sBig;
  u16 (*sHl)[LROW] = (u16(*)[LROW])(sBig + SROWS * LROW);
  u16 (*sGh)[LROW] = sHh;
  u16 (*sGl)[LROW] = sHl;
  float* sC2 = (float*)sBig;

  const int bid  = blockIdx.x;
  const int tid  = threadIdx.x;
  const int lane = tid & 63;
  const int wave = tid >> 6;
  // group members share bid%8 -> same-XCD heuristic for flag/data locality
  const int strip = bid & 15;     // group id (16 batch rows)
  const int part  = bid >> 4;     // member 0..15

  u32* gflag = flags + strip * 16;   // one 64B line per group

  // ---- phase A geometry: [16 rows x 64 cols] over [256 x 1024] (R cols | Z cols) ----
  const int isZ = part >= 8;
  const int ncA = (part & 7) * 64;
  const u16*  WA   = w_hb  + (size_t)(isZ ? 1 : 0) * HID * HID;
  const u16*  WXAh = wx_hi + (size_t)(isZ ? 1 : 0) * HID * DPAD;
  const u16*  WXAl = wx_lo + (size_t)(isZ ? 1 : 0) * HID * DPAD;
  const float* nA  = isZ ? nz : nr;
  const int rowl  = lane & 15;                    // fragment row (batch within strip)
  const int colA  = ncA + wave * 16 + rowl;       // wave = n-tile
  const float biasA = (isZ ? bhz : bhr)[colA];

  // ---- phase B geometry: [16 rows x 32 cols]; waves: n-tile x k-half ----
  const int ncB  = part * 32;
  const u16*  WH   = w_hb  + (size_t)2 * HID * HID;
  const u16*  WXBh = wx_hi + (size_t)2 * HID * DPAD;
  const u16*  WXBl = wx_lo + (size_t)2 * HID * DPAD;
  const int ntB = wave & 1;
  const int khB = wave >> 1;
  const int colB = ncB + ntB * 16 + rowl;
  const float biasB = bhh[colB];

  float h_old[4] = {0.f, 0.f, 0.f, 0.f};   // fp32 state (khB==0 waves own update)

  // zero x-buffer k-pads once (cols 85..103)
  for (int c = tid; c < SROWS * (104 - DIN); c += 256) {
    int row = c / (104 - DIN), k = DIN + c % (104 - DIN);
    sXh[row][k] = 0; sXl[row][k] = 0;
  }
  // stage xA for t=1
  {
    const size_t xoff = (size_t)(strip * SROWS) * DIN;
    for (int c = tid; c < SROWS * DIN; c += 256) {
      int row = c / DIN, k = c - row * DIN;
      float v = x[xoff + c] + nA[xoff + c];
      u16 hi = f2bf(v);
      sXh[row][k] = hi;
      sXl[row][k] = f2bf(v - bf2f(hi));
    }
  }

  for (int t = 1; t <= TSTEPS; ++t) {
    // ---------- phase C (small-ws inline out-projection) for step t-2 ----------
    if (do_c && t >= 2) {
      const int row = strip * SROWS + part;    // 16 rows x 16 parts = all 256 rows
      const int o = tid >> 3, q = tid & 7;
      const int base = row * HID + q * 64;
      float a = 0.f;
      #pragma unroll 8
      for (int k2 = 0; k2 < 64; ++k2) {
        u32 v = ld_u32_llc(&h_pk[base + k2]);
        a += (bf2f((u16)(v >> 16)) + bf2f((u16)(v & 0xFFFFu))) * Wro[(size_t)o * HID + q * 64 + k2];
      }
      __syncthreads();            // sBig (sC2) free of phase-B LDS hazards
      sC2[o * 8 + q] = a;
      if (tid < 8) {
        float a2 = 0.f;
        #pragma unroll 8
        for (int k2 = 0; k2 < 64; ++k2) {
          u32 v = ld_u32_llc(&h_pk[base + (tid - q) * 64 + k2]);   // placeholder never hit
          a2 += 0.f * (float)v;
        }
        // column 32 (recomputed cleanly below)
        float a3 = 0.f;
        const int base2 = row * HID + tid * 64;
        #pragma unroll 8
        for (int k2 = 0; k2 < 64; ++k2) {
          u32 v = ld_u32_llc(&h_pk[base2 + k2]);
          a3 += (bf2f((u16)(v >> 16)) + bf2f((u16)(v & 0xFFFFu))) * Wro[(size_t)32 * HID + tid * 64 + k2];
        }
        sC2[32 * 8 + tid] = a2 + a3;
      }
      __syncthreads();
      if (tid < ODIM) {
        float s = bro[tid];
        #pragma unroll
        for (int q2 = 0; q2 < 8; ++q2) s += sC2[tid * 8 + q2];
        out[(size_t)((t - 2) * NB + row) * ODIM + tid] = s;
      }
      __syncthreads();
    }

    // ================= PHASE A: R and Z =================
    // one-shot split-h strip staging: 16 rows x 512 cols packed u32 = 32KB
    {
      const u64* hsrc = (const u64*)h_pk;       // u64 = 2 packed cols
      u64 hreg[SROWS];
      #pragma unroll
      for (int i = 0; i < SROWS; ++i)
        hreg[i] = ld_u64_llc(&hsrc[(size_t)(strip * SROWS + i) * 256 + tid]);
      #pragma unroll
      for (int i = 0; i < SROWS; ++i) {
        u32 v0 = (u32)hreg[i], v1 = (u32)(hreg[i] >> 32);
        *(u32*)&sHh[i][tid * 2] = (v0 >> 16) | (v1 & 0xFFFF0000u);
        *(u32*)&sHl[i][tid * 2] = (v0 & 0xFFFFu) | (v1 << 16);
      }
    }
    __syncthreads();

    f32x4 accA = {0.f, 0.f, 0.f, 0.f};
    // x-projection (K=96; split x, split Wx)
    #pragma unroll
    for (int ks = 0; ks < 3; ++ks) {
      int kk = ks * 32 + 8 * (lane >> 4);
      bf16x8 wh = bc8(*(const uint4*)&WXAh[(size_t)colA * DPAD + kk]);
      bf16x8 wl = bc8(*(const uint4*)&WXAl[(size_t)colA * DPAD + kk]);
      bf16x8 xh = bc8(*(const uint4*)&sXh[rowl][kk]);
      bf16x8 xl = bc8(*(const uint4*)&sXl[rowl][kk]);
      accA = mfma_bf16(xh, wh, accA);
      accA = mfma_bf16(xl, wh, accA);
      accA = mfma_bf16(xh, wl, accA);
    }
    // h GEMM (K=512, split h)
    #pragma unroll
    for (int kk16 = 0; kk16 < 16; ++kk16) {
      int k = kk16 * 32 + 8 * (lane >> 4);
      bf16x8 bw = bc8(*(const uint4*)&WA[(size_t)colA * HID + k]);
      bf16x8 ah = bc8(*(const uint4*)&sHh[rowl][k]);
      bf16x8 al = bc8(*(const uint4*)&sHl[rowl][k]);
      accA = mfma_bf16(ah, bw, accA);
      accA = mfma_bf16(al, bw, accA);
    }

    // epilogue A (precise h for R*h straight from the staged LDS strip)
    #pragma unroll
    for (int r = 0; r < 4; ++r) {
      int rowm = (lane >> 4) * 4 + r;
      int grow = strip * SROWS + rowm;
      float val = fsigmoid(accA[r] + biasA);
      size_t idx = (size_t)grow * HID + colA;
      if (!isZ) {
        float hcur = bf2f(sHh[rowm][colA]) + bf2f(sHl[rowm][colA]);
        float g = val * hcur;
        u16 gh = f2bf(g);
        u16 gl = f2bf(g - bf2f(gh));
        st_u32_llc(&g_pk[idx], ((u32)gh << 16) | (u32)gl);
      } else {
        st_f32_llc(&z_buf[idx], val);
      }
    }

    // arrive(2t-1): __syncthreads drains all waves' stores (vmcnt 0) -> relaxed flag is safe
    __syncthreads();
    if (tid == 0) st_u32_llc(&gflag[part], (u32)(2 * t - 1));

    // overlap: stage xB(t) during barrier wait
    {
      const size_t xoff = (size_t)((t - 1) * NB + strip * SROWS) * DIN;
      for (int c = tid; c < SROWS * DIN; c += 256) {
        int row = c / DIN, k = c - row * DIN;
        float v = x[xoff + c] + nh[xoff + c];
        u16 hi = f2bf(v);
        sXh[row][k] = hi;
        sXl[row][k] = f2bf(v - bf2f(hi));
      }
    }
    // wait(2t-1): poll one 64B line (lanes 0..15)
    if (wave == 0) {
      const u32 target = (u32)(2 * t - 1);
      for (;;) {
        u32 a = (lane < 16) ? ld_u32_llc(&gflag[lane]) : target;
        if (__all(a >= target)) break;
      }
    }
    __syncthreads();

    // ================= PHASE B: Hh + state update =================
    // early: Z for the update (khB==0 waves)
    float zv[4];
    if (khB == 0) {
      #pragma unroll
      for (int r = 0; r < 4; ++r) {
        int brow = strip * SROWS + (lane >> 4) * 4 + r;
        zv[r] = ld_f32_llc(&z_buf[(size_t)brow * HID + colB]);
      }
    }
    // one-shot split-g strip staging
    {
      const u64* gsrc = (const u64*)g_pk;
      u64 greg[SROWS];
      #pragma unroll
      for (int i = 0; i < SROWS; ++i)
        greg[i] = ld_u64_llc(&gsrc[(size_t)(strip * SROWS + i) * 256 + tid]);
      #pragma unroll
      for (int i = 0; i < SROWS; ++i) {
        u32 v0 = (u32)greg[i], v1 = (u32)(greg[i] >> 32);
        *(u32*)&sGh[i][tid * 2] = (v0 >> 16) | (v1 & 0xFFFF0000u);
        *(u32*)&sGl[i][tid * 2] = (v0 & 0xFFFFu) | (v1 << 16);
      }
    }
    __syncthreads();

    f32x4 accB = {0.f, 0.f, 0.f, 0.f};
    if (khB == 0) {   // x-projection on k-lower waves
      #pragma unroll
      for (int ks = 0; ks < 3; ++ks) {
        int kk = ks * 32 + 8 * (lane >> 4);
        bf16x8 wh = bc8(*(const uint4*)&WXBh[(size_t)colB * DPAD + kk]);
        bf16x8 wl = bc8(*(const uint4*)&WXBl[(size_t)colB * DPAD + kk]);
        bf16x8 xh = bc8(*(const uint4*)&sXh[rowl][kk]);
        bf16x8 xl = bc8(*(const uint4*)&sXl[rowl][kk]);
        accB = mfma_bf16(xh, wh, accB);
        accB = mfma_bf16(xl, wh, accB);
        accB = mfma_bf16(xh, wl, accB);
      }
    }
    #pragma unroll
    for (int f = 0; f < 8; ++f) {
      int k = khB * 256 + f * 32 + 8 * (lane >> 4);
      bf16x8 bw = bc8(*(const uint4*)&WH[(size_t)colB * HID + k]);
      bf16x8 gh = bc8(*(const uint4*)&sGh[rowl][k]);
      bf16x8 gl = bc8(*(const uint4*)&sGl[rowl][k]);
      accB = mfma_bf16(gh, bw, accB);
      accB = mfma_bf16(gl, bw, accB);
    }
    if (khB == 1) *(f32x4*)&sC[ntB][lane][0] = accB;
    __syncthreads();

    u16 hiv[4] = {0, 0, 0, 0};
    if (khB == 0) {
      f32x4 oth = *(const f32x4*)&sC[ntB][lane][0];
      accB[0] += oth[0]; accB[1] += oth[1]; accB[2] += oth[2]; accB[3] += oth[3];
      #pragma unroll
      for (int r = 0; r < 4; ++r) {
        int brow = strip * SROWS + (lane >> 4) * 4 + r;
        float hh = ftanh(accB[r] + biasB);
        float hn = zv[r] * h_old[r] + (1.0f - zv[r]) * hh;
        h_old[r] = hn;
        u16 hi = f2bf(hn);
        u16 lo = f2bf(hn - bf2f(hi));
        hiv[r] = hi;
        st_u32_llc(&h_pk[(size_t)brow * HID + colB], ((u32)hi << 16) | (u32)lo);
      }
    }

    // arrive(2t): drains ONLY the LLC exchange stores (hs_out moved after the flag)
    __syncthreads();
    if (tid == 0) st_u32_llc(&gflag[part], (u32)(2 * t));

    // off the critical path: hs_out history (big-ws) — HBM acks complete under the wait
    if (hs_out && khB == 0) {
      #pragma unroll
      for (int r = 0; r < 4; ++r) {
        int brow = strip * SROWS + (lane >> 4) * 4 + r;
        hs_out[(size_t)((t - 1) * NB + brow) * HID + colB] = hiv[r];
      }
    }
    // overlap: stage xA(t+1) during barrier wait
    if (t < TSTEPS) {
      const size_t xoff = (size_t)(t * NB + strip * SROWS) * DIN;
      for (int c = tid; c < SROWS * DIN; c += 256) {
        int row = c / DIN, k = c - row * DIN;
        float v = x[xoff + c] + nA[xoff + c];
        u16 hi = f2bf(v);
        sXh[row][k] = hi;
        sXl[row][k] = f2bf(v - bf2f(hi));
      }
    }
    // wait(2t)
    if (wave == 0) {
      const u32 target = (u32)(2 * t);
      for (;;) {
        u32 a = (lane < 16) ? ld_u32_llc(&gflag[lane]) : target;
        if (__all(a >= target)) break;
      }
    }
    __syncthreads();
  }

  // ---- final phase C (small-ws) for t = TSTEPS ----
  if (do_c) {
    const int row = strip * SROWS + part;
    const int o = tid >> 3, q = tid & 7;
    const int base = row * HID + q * 64;
    float a = 0.f;
    #pragma unroll 8
    for (int k2 = 0; k2 < 64; ++k2) {
      u32 v = ld_u32_llc(&h_pk[base + k2]);
      a += (bf2f((u16)(v >> 16)) + bf2f((u16)(v & 0xFFFFu))) * Wro[(size_t)o * HID + q * 64 + k2];
    }
    __syncthreads();
    sC2[o * 8 + q] = a;
    if (tid < 8) {
      float a2 = 0.f;
      const int base2 = row * HID + tid * 64;
      #pragma unroll 8
      for (int k2 = 0; k2 < 64; ++k2) {
        u32 v = ld_u32_llc(&h_pk[base2 + k2]);
        a2 += (bf2f((u16)(v >> 16)) + bf2f((u16)(v & 0xFFFFu))) * Wro[(size_t)32 * HID + tid * 64 + k2];
      }
      sC2[32 * 8 + tid] = a2;
    }
    __syncthreads();
    if (tid < ODIM) {
      float s = bro[tid];
      #pragma unroll
      for (int q2 = 0; q2 < 8; ++q2) s += sC2[tid * 8 + q2];
      out[(size_t)((TSTEPS - 1) * NB + row) * ODIM + tid] = s;
    }
  }
}

// ---------------- output projection (big-ws path) ----------------
__global__ void __launch_bounds__(256) out_kernel(
    const u16* __restrict__ hs_out,
    const u16* __restrict__ w_rob, const float* __restrict__ b_ro,
    float* __restrict__ out)
{
  __shared__ __attribute__((aligned(16))) u16 sOh[128][72];

  const int m0   = blockIdx.x * 128;
  const int tid  = threadIdx.x;
  const int lane = tid & 63, wave = tid >> 6;

  f32x4 acc[2][3];
  for (int a = 0; a < 2; ++a) for (int b = 0; b < 3; ++b) acc[a][b] = {0.f, 0.f, 0.f, 0.f};

  for (int kc = 0; kc < 8; ++kc) {
    __syncthreads();
    #pragma unroll
    for (int i = 0; i < 4; ++i) {
      int c = tid + 256 * i; int row = c >> 3, seg = c & 7;
      *(uint4*)&sOh[row][seg * 8] =
        *(const uint4*)&hs_out[(size_t)(m0 + row) * HID + kc * 64 + seg * 8];
    }
    __syncthreads();
    #pragma unroll
    for (int ks = 0; ks < 2; ++ks) {
      int klocal = ks * 32 + 8 * (lane >> 4);
      int kglob  = kc * 64 + klocal;
      bf16x8 ah[2];
      #pragma unroll
      for (int mf = 0; mf < 2; ++mf) {
        int rowl = wave * 32 + mf * 16 + (lane & 15);
        ah[mf] = bc8(*(const uint4*)&sOh[rowl][klocal]);
      }
      #pragma unroll
      for (int nf = 0; nf < 3; ++nf) {
        int wrow = nf * 16 + (lane & 15);
        bf16x8 bw = bc8(*(const uint4*)&w_rob[(size_t)wrow * HID + kglob]);
        #pragma unroll
        for (int mf = 0; mf < 2; ++mf)
          acc[mf][nf] = mfma_bf16(ah[mf], bw, acc[mf][nf]);
      }
    }
  }
  for (int nf = 0; nf < 3; ++nf) {
    int o = nf * 16 + (lane & 15);
    if (o < ODIM) {
      float bb = b_ro[o];
      for (int mf = 0; mf < 2; ++mf)
        for (int r = 0; r < 4; ++r) {
          int R = m0 + wave * 32 + mf * 16 + (lane >> 4) * 4 + r;
          out[(size_t)R * ODIM + o] = acc[mf][nf][r] + bb;
        }
    }
  }
}

// ---------------- launcher ----------------
extern "C" void kernel_launch(void* const* d_in, const int* in_sizes, int n_in,
                              void* d_out, int out_size, void* d_ws, size_t ws_size,
                              hipStream_t stream)
{
  const float* x   = (const float*)d_in[0];
  const float* nr  = (const float*)d_in[1];
  const float* nz  = (const float*)d_in[2];
  const float* nh  = (const float*)d_in[3];
  const float* Wxr = (const float*)d_in[4];
  const float* Wxz = (const float*)d_in[5];
  const float* Wxh = (const float*)d_in[6];
  const float* Whr = (const float*)d_in[7];
  const float* bhr = (const float*)d_in[8];
  const float* Whz = (const float*)d_in[9];
  const float* bhz = (const float*)d_in[10];
  const float* Whh = (const float*)d_in[11];
  const float* bhh = (const float*)d_in[12];
  const float* Wro = (const float*)d_in[13];
  const float* bro = (const float*)d_in[14];
  float* out = (float*)d_out;

  char* ws = (char*)d_ws;
  size_t off = 0;
  auto alloc = [&](size_t bytes) -> char* {
    char* p = ws + off;
    off += (bytes + 255) & ~(size_t)255;
    return p;
  };
  u32*  h_pk  = (u32*) alloc((size_t)NB * HID * 4);       // packed hi|lo h state
  u32*  g_pk  = (u32*) alloc((size_t)NB * HID * 4);       // packed hi|lo R*h
  float* z_buf= (float*)alloc((size_t)NB * HID * 4);
  u16*  w_hb  = (u16*) alloc((size_t)3 * HID * HID * 2);
  u16*  wx_hi = (u16*) alloc((size_t)3 * HID * DPAD * 2);
  u16*  wx_lo = (u16*) alloc((size_t)3 * HID * DPAD * 2);
  u16*  w_rob = (u16*) alloc((size_t)OPAD * HID * 2);
  u32*  flags = (u32*) alloc((size_t)16 * 16 * 4);        // 16 groups x one 64B line
  size_t small_need = off;
  if (ws_size < small_need) return;   // fail numerically, never scribble

  u16* hs_out = (u16*)(ws + off);
  size_t big_need = off + (size_t)TBROWS * HID * 2 + 256;
  bool big = (ws_size >= big_need);
  if (!big) hs_out = nullptr;

  hipMemsetAsync(flags, 0, (size_t)16 * 16 * 4, stream);
  hipMemsetAsync(h_pk,  0, (size_t)NB * HID * 4, stream);   // h0 = 0

  prep_kernel<<<512, 256, 0, stream>>>(Whr, Whz, Whh, Wxr, Wxz, Wxh, Wro,
                                       w_hb, wx_hi, wx_lo, w_rob);

  recur_kernel<<<NBLK, 256, 0, stream>>>(
      x, nr, nz, nh, bhr, bhz, bhh, wx_hi, wx_lo, w_hb,
      h_pk, g_pk, z_buf, flags, hs_out, Wro, bro, out, big ? 0 : 1);

  if (big)
    out_kernel<<<TBROWS / 128, 256, 0, stream>>>(hs_out, w_rob, bro, out);
}